// Round 6
// baseline (122.894 us; speedup 1.0000x reference)
//
#include <hip/hip_runtime.h>
#include <math.h>

#define BB 8
#define NN 256
#define DD 128

// ---------------- Kernel A: h = node@Wn+bn, ti = node@We1[:D]+be1, aj = node@We1[D:2D]
// 256 threads, 4 rows/block. Thread: cp=tid&63 (d-pair), rp=(tid>>6)&1 (row-pair), ks=tid>>7 (k-half).
#define PR 4
__global__ __launch_bounds__(256) void prep_kernel(
    const float* __restrict__ node, const float* __restrict__ Wn,
    const float* __restrict__ bn, const float* __restrict__ We1,
    const float* __restrict__ be1, float* __restrict__ h,
    float* __restrict__ ti, float* __restrict__ aj)
{
    __shared__ __align__(16) float sx[PR * DD];
    __shared__ float s_acc[12 * 128];
    int tid = threadIdx.x;
    int cp = tid & 63;
    int rp = (tid >> 6) & 1;
    int ks = tid >> 7;
    int row0 = blockIdx.x * PR;
    if (tid < 128) {
        int rr = tid >> 5, cc = (tid & 31) << 2;
        *(float4*)&sx[rr * DD + cc] = *(const float4*)&node[(size_t)(row0 + rr) * DD + cc];
    }
    __syncthreads();
    int d0 = cp << 1;
    int ra = rp << 1, rb = ra | 1;
    float ah[2] = {0.f, 0.f}, ai[2] = {0.f, 0.f}, ajc[2] = {0.f, 0.f};
    float bh[2] = {0.f, 0.f}, bi[2] = {0.f, 0.f}, bjc[2] = {0.f, 0.f};
    int k0 = ks << 6;
    for (int k = k0; k < k0 + 64; k += 4) {
        float4 xa = *(const float4*)&sx[ra * DD + k];
        float4 xb = *(const float4*)&sx[rb * DD + k];
        #pragma unroll
        for (int kk = 0; kk < 4; ++kk) {
            float2 w0 = *(const float2*)&Wn [(size_t)(k + kk) * DD + d0];
            float2 w1 = *(const float2*)&We1[(size_t)(k + kk) * DD + d0];
            float2 w2 = *(const float2*)&We1[(size_t)(DD + k + kk) * DD + d0];
            float xav = (kk == 0) ? xa.x : (kk == 1) ? xa.y : (kk == 2) ? xa.z : xa.w;
            float xbv = (kk == 0) ? xb.x : (kk == 1) ? xb.y : (kk == 2) ? xb.z : xb.w;
            ah[0] = fmaf(xav, w0.x, ah[0]); ah[1] = fmaf(xav, w0.y, ah[1]);
            ai[0] = fmaf(xav, w1.x, ai[0]); ai[1] = fmaf(xav, w1.y, ai[1]);
            ajc[0] = fmaf(xav, w2.x, ajc[0]); ajc[1] = fmaf(xav, w2.y, ajc[1]);
            bh[0] = fmaf(xbv, w0.x, bh[0]); bh[1] = fmaf(xbv, w0.y, bh[1]);
            bi[0] = fmaf(xbv, w1.x, bi[0]); bi[1] = fmaf(xbv, w1.y, bi[1]);
            bjc[0] = fmaf(xbv, w2.x, bjc[0]); bjc[1] = fmaf(xbv, w2.y, bjc[1]);
        }
    }
    int p = (rp << 6) | cp;
    if (ks == 1) {
        s_acc[0 * 128 + p] = ah[0];  s_acc[1 * 128 + p] = ah[1];
        s_acc[2 * 128 + p] = ai[0];  s_acc[3 * 128 + p] = ai[1];
        s_acc[4 * 128 + p] = ajc[0]; s_acc[5 * 128 + p] = ajc[1];
        s_acc[6 * 128 + p] = bh[0];  s_acc[7 * 128 + p] = bh[1];
        s_acc[8 * 128 + p] = bi[0];  s_acc[9 * 128 + p] = bi[1];
        s_acc[10 * 128 + p] = bjc[0]; s_acc[11 * 128 + p] = bjc[1];
    }
    __syncthreads();
    if (ks == 0) {
        float2 bn2  = *(const float2*)&bn[d0];
        float2 be12 = *(const float2*)&be1[d0];
        ah[0] += s_acc[0 * 128 + p] + bn2.x;  ah[1] += s_acc[1 * 128 + p] + bn2.y;
        ai[0] += s_acc[2 * 128 + p] + be12.x; ai[1] += s_acc[3 * 128 + p] + be12.y;
        ajc[0] += s_acc[4 * 128 + p];         ajc[1] += s_acc[5 * 128 + p];
        bh[0] += s_acc[6 * 128 + p] + bn2.x;  bh[1] += s_acc[7 * 128 + p] + bn2.y;
        bi[0] += s_acc[8 * 128 + p] + be12.x; bi[1] += s_acc[9 * 128 + p] + be12.y;
        bjc[0] += s_acc[10 * 128 + p];        bjc[1] += s_acc[11 * 128 + p];
        size_t oa = (size_t)(row0 + ra) * DD + d0;
        size_t ob = (size_t)(row0 + rb) * DD + d0;
        *(float2*)&h [oa] = make_float2(ah[0], ah[1]);
        *(float2*)&ti[oa] = make_float2(ai[0], ai[1]);
        *(float2*)&aj[oa] = make_float2(ajc[0], ajc[1]);
        *(float2*)&h [ob] = make_float2(bh[0], bh[1]);
        *(float2*)&ti[ob] = make_float2(bi[0], bi[1]);
        *(float2*)&aj[ob] = make_float2(bjc[0], bjc[1]);
    }
}

// ---------------- Kernel B (fused): scores + softmax + msg=w@h + relu(msg@Wa+ba) + residual + LN
// 256 threads, IT=2 rows/block, grid = B*N/2 = 1024 (4 blocks/CU, single full-residency round).
// Phase 1 has NO LDS: thread j streams its own aj row from global (L1/L2 resident).
#define IT 2
__global__ __launch_bounds__(256, 4) void edge_kernel(
    const float* __restrict__ ti, const float* __restrict__ ajp,
    const float* __restrict__ rel, const int* __restrict__ adj,
    const float* __restrict__ We1, const float* __restrict__ We2,
    const float* __restrict__ be2, const float* __restrict__ h,
    const float* __restrict__ Wa, const float* __restrict__ ba,
    const float* __restrict__ node, const float* __restrict__ gamma,
    const float* __restrict__ beta, float* __restrict__ out)
{
    __shared__ __align__(16) float s_part[2048];    // 8 KB partial buffer (phases 3/4)
    __shared__ __align__(16) float s_w[NN * IT];    // transposed w: [j][r]
    __shared__ __align__(16) float s_m[DD * IT];    // transposed msg: [k][r]
    __shared__ float s_red[IT][4];
    __shared__ float s_red2[IT][2][2];

    int tid = threadIdx.x;
    int b  = blockIdx.x / (NN / IT);
    int i0 = (blockIdx.x % (NN / IT)) * IT;
    int j = tid;

    // ---- Phase 1: edge scores; per-lane state for 2 rows, aj row streamed from global
    const float2* rel2 = (const float2*)rel;
    float rx[IT], ry[IT], dsv[IT], sc[IT];
    int msk[IT];
    float be2v = be2[0];
    #pragma unroll
    for (int r = 0; r < IT; ++r) {
        float2 rp = rel2[(size_t)(b * NN + i0 + r) * NN + j];
        rx[r] = rp.x; ry[r] = rp.y;
        dsv[r] = sqrtf(rp.x * rp.x + rp.y * rp.y);
        msk[r] = adj[(size_t)(b * NN + i0 + r) * NN + j];
        sc[r] = be2v;
    }
    const float* TI = ti + (size_t)(b * NN + i0) * DD;          // wave-uniform base -> s_load
    const float* W0 = We1 + (size_t)(2 * DD + 0) * DD;
    const float* W1 = We1 + (size_t)(2 * DD + 1) * DD;
    const float* W2 = We1 + (size_t)(2 * DD + 2) * DD;
    const float* AJ = ajp + (size_t)(b * NN + j) * DD;          // per-lane row

    #pragma unroll 8
    for (int g = 0; g < 32; ++g) {
        int dd = g << 2;
        float4 a  = *(const float4*)&AJ[dd];        // global, L1-resident after first line touch
        float4 w0 = *(const float4*)&W0[dd];        // uniform -> s_load_dwordx4
        float4 w1 = *(const float4*)&W1[dd];
        float4 w2 = *(const float4*)&W2[dd];
        float4 e2 = *(const float4*)&We2[dd];
        #pragma unroll
        for (int r = 0; r < IT; ++r) {
            float4 t = *(const float4*)&TI[r * DD + dd];        // uniform -> s_load
            float v0;
            v0 = fmaf(rx[r], w0.x, t.x + a.x); v0 = fmaf(ry[r], w1.x, v0); v0 = fmaf(dsv[r], w2.x, v0);
            sc[r] = fmaf(fmaxf(v0, 0.f), e2.x, sc[r]);
            v0 = fmaf(rx[r], w0.y, t.y + a.y); v0 = fmaf(ry[r], w1.y, v0); v0 = fmaf(dsv[r], w2.y, v0);
            sc[r] = fmaf(fmaxf(v0, 0.f), e2.y, sc[r]);
            v0 = fmaf(rx[r], w0.z, t.z + a.z); v0 = fmaf(ry[r], w1.z, v0); v0 = fmaf(dsv[r], w2.z, v0);
            sc[r] = fmaf(fmaxf(v0, 0.f), e2.z, sc[r]);
            v0 = fmaf(rx[r], w0.w, t.w + a.w); v0 = fmaf(ry[r], w1.w, v0); v0 = fmaf(dsv[r], w2.w, v0);
            sc[r] = fmaf(fmaxf(v0, 0.f), e2.w, sc[r]);
        }
    }
    #pragma unroll
    for (int r = 0; r < IT; ++r) if (msk[r] == 0) sc[r] = -3.0e38f;

    // ---- Phase 2: masked softmax across j (4 waves)
    int wave = tid >> 6, lane = tid & 63;
    float e[IT];
    {
        float m0 = sc[0], m1 = sc[1];
        for (int off = 32; off > 0; off >>= 1) {
            m0 = fmaxf(m0, __shfl_xor(m0, off));
            m1 = fmaxf(m1, __shfl_xor(m1, off));
        }
        if (lane == 0) { s_red[0][wave] = m0; s_red[1][wave] = m1; }
    }
    __syncthreads();
    #pragma unroll
    for (int r = 0; r < IT; ++r) {
        float M = fmaxf(fmaxf(s_red[r][0], s_red[r][1]), fmaxf(s_red[r][2], s_red[r][3]));
        e[r] = (msk[r] == 0) ? 0.f : __expf(sc[r] - M);
    }
    __syncthreads();
    {
        float s0 = e[0], s1 = e[1];
        for (int off = 32; off > 0; off >>= 1) {
            s0 += __shfl_xor(s0, off);
            s1 += __shfl_xor(s1, off);
        }
        if (lane == 0) { s_red[0][wave] = s0; s_red[1][wave] = s1; }
    }
    __syncthreads();
    {
        float S0 = s_red[0][0] + s_red[0][1] + s_red[0][2] + s_red[0][3];
        float S1 = s_red[1][0] + s_red[1][1] + s_red[1][2] + s_red[1][3];
        float w0 = e[0] * __builtin_amdgcn_rcpf(S0);
        float w1 = e[1] * __builtin_amdgcn_rcpf(S1);
        *(float2*)&s_w[j * 2] = make_float2(w0, w1);   // transposed store
    }
    __syncthreads();

    // ---- Phase 3: msg = w@h via slice partials. Thread: g3=tid&31 (d4-group), sl=tid>>5 (j-slice)
    int g3 = tid & 31, sl = tid >> 5;
    {
        const float* hb = h + (size_t)b * NN * DD;
        float4 acc0 = make_float4(0.f, 0.f, 0.f, 0.f);
        float4 acc1 = make_float4(0.f, 0.f, 0.f, 0.f);
        for (int q = 0; q < 32; ++q) {
            int jj = (sl << 5) + q;
            float4 hv = *(const float4*)&hb[(size_t)jj * DD + (g3 << 2)];
            float2 wv = *(const float2*)&s_w[jj * 2];
            acc0.x = fmaf(wv.x, hv.x, acc0.x); acc0.y = fmaf(wv.x, hv.y, acc0.y);
            acc0.z = fmaf(wv.x, hv.z, acc0.z); acc0.w = fmaf(wv.x, hv.w, acc0.w);
            acc1.x = fmaf(wv.y, hv.x, acc1.x); acc1.y = fmaf(wv.y, hv.y, acc1.y);
            acc1.z = fmaf(wv.y, hv.z, acc1.z); acc1.w = fmaf(wv.y, hv.w, acc1.w);
        }
        *(float4*)&s_part[(((sl << 5) + g3) * 2 + 0) << 2] = acc0;
        *(float4*)&s_part[(((sl << 5) + g3) * 2 + 1) << 2] = acc1;
    }
    __syncthreads();
    {
        int r = tid >> 7, d = tid & 127;               // 256 outputs, one per thread
        float s = 0.f;
        #pragma unroll
        for (int s2 = 0; s2 < 8; ++s2)
            s += s_part[((((s2 << 5) + (d >> 2)) * 2 + r) << 2) + (d & 3)];
        s_m[d * 2 + r] = s;                            // transposed msg
    }
    __syncthreads();

    // ---- Phase 4: agg = relu(msg@Wa+ba). Thread: g3 (d4-group), sl (k-slice of 16)
    {
        float4 ac0 = make_float4(0.f, 0.f, 0.f, 0.f);
        float4 ac1 = make_float4(0.f, 0.f, 0.f, 0.f);
        for (int q = 0; q < 16; ++q) {
            int k = (sl << 4) + q;
            float4 wa = *(const float4*)&Wa[(size_t)k * DD + (g3 << 2)];
            float2 mv = *(const float2*)&s_m[k * 2];
            ac0.x = fmaf(mv.x, wa.x, ac0.x); ac0.y = fmaf(mv.x, wa.y, ac0.y);
            ac0.z = fmaf(mv.x, wa.z, ac0.z); ac0.w = fmaf(mv.x, wa.w, ac0.w);
            ac1.x = fmaf(mv.y, wa.x, ac1.x); ac1.y = fmaf(mv.y, wa.y, ac1.y);
            ac1.z = fmaf(mv.y, wa.z, ac1.z); ac1.w = fmaf(mv.y, wa.w, ac1.w);
        }
        __syncthreads();
        *(float4*)&s_part[(((sl << 5) + g3) * 2 + 0) << 2] = ac0;
        *(float4*)&s_part[(((sl << 5) + g3) * 2 + 1) << 2] = ac1;
    }
    __syncthreads();

    // ---- Phase 5: reduce, bias+relu, residual, LayerNorm
    {
        int r = tid >> 7, d = tid & 127;
        float agg = 0.f;
        #pragma unroll
        for (int s2 = 0; s2 < 8; ++s2)
            agg += s_part[((((s2 << 5) + (d >> 2)) * 2 + r) << 2) + (d & 3)];
        float x = node[(size_t)(b * NN + i0 + r) * DD + d] + fmaxf(agg + ba[d], 0.f);
        int wh = (tid >> 6) & 1;
        float s1 = x, s2v = x * x;
        for (int off = 32; off > 0; off >>= 1) {
            s1 += __shfl_xor(s1, off);
            s2v += __shfl_xor(s2v, off);
        }
        if (lane == 0) { s_red2[r][wh][0] = s1; s_red2[r][wh][1] = s2v; }
        __syncthreads();
        float t1 = s_red2[r][0][0] + s_red2[r][1][0];
        float t2 = s_red2[r][0][1] + s_red2[r][1][1];
        float mu  = t1 * (1.0f / DD);
        float var = t2 * (1.0f / DD) - mu * mu;
        float inv = rsqrtf(var + 1e-5f);
        out[(size_t)(b * NN + i0 + r) * DD + d] = (x - mu) * inv * gamma[d] + beta[d];
    }
}

extern "C" void kernel_launch(void* const* d_in, const int* in_sizes, int n_in,
                              void* d_out, int out_size, void* d_ws, size_t ws_size,
                              hipStream_t stream) {
    const float* node = (const float*)d_in[0];
    const int*   adj  = (const int*)d_in[1];
    const float* rel  = (const float*)d_in[2];
    const float* Wn   = (const float*)d_in[3];
    const float* bn   = (const float*)d_in[4];
    const float* We1  = (const float*)d_in[5];
    const float* be1  = (const float*)d_in[6];
    const float* We2  = (const float*)d_in[7];
    const float* be2  = (const float*)d_in[8];
    const float* Wa   = (const float*)d_in[9];
    const float* ba   = (const float*)d_in[10];
    const float* gamma = (const float*)d_in[11];
    const float* beta  = (const float*)d_in[12];
    float* out = (float*)d_out;

    float* ws  = (float*)d_ws;
    const int ROWS = BB * NN * DD;          // 262144
    float* h   = ws;
    float* ti  = ws + ROWS;
    float* aj  = ws + 2 * ROWS;

    prep_kernel<<<BB * NN / PR, 256, 0, stream>>>(node, Wn, bn, We1, be1, h, ti, aj);
    edge_kernel<<<BB * NN / IT, 256, 0, stream>>>(ti, aj, rel, adj, We1, We2, be2,
                                                  h, Wa, ba, node, gamma, beta, out);
}

// Round 7
// 117.079 us; speedup vs baseline: 1.0497x; 1.0497x over previous
//
#include <hip/hip_runtime.h>
#include <math.h>

#define BB 8
#define NN 256
#define DD 128

// ---------------- Kernel A: h = node@Wn+bn, ti = node@We1[:D]+be1, aj = node@We1[D:2D]
// 256 threads, 4 rows/block. Thread: cp=tid&63 (d-pair), rp=(tid>>6)&1 (row-pair), ks=tid>>7 (k-half).
#define PR 4
__global__ __launch_bounds__(256) void prep_kernel(
    const float* __restrict__ node, const float* __restrict__ Wn,
    const float* __restrict__ bn, const float* __restrict__ We1,
    const float* __restrict__ be1, float* __restrict__ h,
    float* __restrict__ ti, float* __restrict__ aj)
{
    __shared__ __align__(16) float sx[PR * DD];
    __shared__ float s_acc[12 * 128];
    int tid = threadIdx.x;
    int cp = tid & 63;
    int rp = (tid >> 6) & 1;
    int ks = tid >> 7;
    int row0 = blockIdx.x * PR;
    if (tid < 128) {
        int rr = tid >> 5, cc = (tid & 31) << 2;
        *(float4*)&sx[rr * DD + cc] = *(const float4*)&node[(size_t)(row0 + rr) * DD + cc];
    }
    __syncthreads();
    int d0 = cp << 1;
    int ra = rp << 1, rb = ra | 1;
    float ah[2] = {0.f, 0.f}, ai[2] = {0.f, 0.f}, ajc[2] = {0.f, 0.f};
    float bh[2] = {0.f, 0.f}, bi[2] = {0.f, 0.f}, bjc[2] = {0.f, 0.f};
    int k0 = ks << 6;
    for (int k = k0; k < k0 + 64; k += 4) {
        float4 xa = *(const float4*)&sx[ra * DD + k];
        float4 xb = *(const float4*)&sx[rb * DD + k];
        #pragma unroll
        for (int kk = 0; kk < 4; ++kk) {
            float2 w0 = *(const float2*)&Wn [(size_t)(k + kk) * DD + d0];
            float2 w1 = *(const float2*)&We1[(size_t)(k + kk) * DD + d0];
            float2 w2 = *(const float2*)&We1[(size_t)(DD + k + kk) * DD + d0];
            float xav = (kk == 0) ? xa.x : (kk == 1) ? xa.y : (kk == 2) ? xa.z : xa.w;
            float xbv = (kk == 0) ? xb.x : (kk == 1) ? xb.y : (kk == 2) ? xb.z : xb.w;
            ah[0] = fmaf(xav, w0.x, ah[0]); ah[1] = fmaf(xav, w0.y, ah[1]);
            ai[0] = fmaf(xav, w1.x, ai[0]); ai[1] = fmaf(xav, w1.y, ai[1]);
            ajc[0] = fmaf(xav, w2.x, ajc[0]); ajc[1] = fmaf(xav, w2.y, ajc[1]);
            bh[0] = fmaf(xbv, w0.x, bh[0]); bh[1] = fmaf(xbv, w0.y, bh[1]);
            bi[0] = fmaf(xbv, w1.x, bi[0]); bi[1] = fmaf(xbv, w1.y, bi[1]);
            bjc[0] = fmaf(xbv, w2.x, bjc[0]); bjc[1] = fmaf(xbv, w2.y, bjc[1]);
        }
    }
    int p = (rp << 6) | cp;
    if (ks == 1) {
        s_acc[0 * 128 + p] = ah[0];  s_acc[1 * 128 + p] = ah[1];
        s_acc[2 * 128 + p] = ai[0];  s_acc[3 * 128 + p] = ai[1];
        s_acc[4 * 128 + p] = ajc[0]; s_acc[5 * 128 + p] = ajc[1];
        s_acc[6 * 128 + p] = bh[0];  s_acc[7 * 128 + p] = bh[1];
        s_acc[8 * 128 + p] = bi[0];  s_acc[9 * 128 + p] = bi[1];
        s_acc[10 * 128 + p] = bjc[0]; s_acc[11 * 128 + p] = bjc[1];
    }
    __syncthreads();
    if (ks == 0) {
        float2 bn2  = *(const float2*)&bn[d0];
        float2 be12 = *(const float2*)&be1[d0];
        ah[0] += s_acc[0 * 128 + p] + bn2.x;  ah[1] += s_acc[1 * 128 + p] + bn2.y;
        ai[0] += s_acc[2 * 128 + p] + be12.x; ai[1] += s_acc[3 * 128 + p] + be12.y;
        ajc[0] += s_acc[4 * 128 + p];         ajc[1] += s_acc[5 * 128 + p];
        bh[0] += s_acc[6 * 128 + p] + bn2.x;  bh[1] += s_acc[7 * 128 + p] + bn2.y;
        bi[0] += s_acc[8 * 128 + p] + be12.x; bi[1] += s_acc[9 * 128 + p] + be12.y;
        bjc[0] += s_acc[10 * 128 + p];        bjc[1] += s_acc[11 * 128 + p];
        size_t oa = (size_t)(row0 + ra) * DD + d0;
        size_t ob = (size_t)(row0 + rb) * DD + d0;
        *(float2*)&h [oa] = make_float2(ah[0], ah[1]);
        *(float2*)&ti[oa] = make_float2(ai[0], ai[1]);
        *(float2*)&aj[oa] = make_float2(ajc[0], ajc[1]);
        *(float2*)&h [ob] = make_float2(bh[0], bh[1]);
        *(float2*)&ti[ob] = make_float2(bi[0], bi[1]);
        *(float2*)&aj[ob] = make_float2(bjc[0], bjc[1]);
    }
}

// ---------------- Kernel B (fused): scores + softmax + msg=w@h + relu(msg@Wa+ba) + residual + LN
// IT=4 rows/block, 256 threads, grid = B*N/4 = 512 (2 blocks/CU).
#define IT 4
__global__ __launch_bounds__(256, 2) void edge_kernel(
    const float* __restrict__ ti, const float* __restrict__ ajp,
    const float* __restrict__ rel, const int* __restrict__ adj,
    const float* __restrict__ We1, const float* __restrict__ We2,
    const float* __restrict__ be2, const float* __restrict__ h,
    const float* __restrict__ Wa, const float* __restrict__ ba,
    const float* __restrict__ node, const float* __restrict__ gamma,
    const float* __restrict__ beta, float* __restrict__ out)
{
    __shared__ __align__(16) float s_buf[NN * 32];  // 32 KB: aj chunks (phase 1), partials (phases 3/4)
    __shared__ __align__(16) float s_w[NN * 4];     // w transposed: [j][r]
    __shared__ __align__(16) float s_m[DD * 4];     // msg transposed: [k][r]
    __shared__ float s_red[IT][4];
    __shared__ float s_red2[IT][2][2];

    int tid = threadIdx.x;
    int b  = blockIdx.x >> 6;                 // 64 blocks per batch
    int i0 = (blockIdx.x & 63) << 2;
    int j = tid;

    // ---- Phase 1: edge scores for 4 rows; lane owns column j
    const float2* rel2 = (const float2*)rel;
    float rx[IT], ry[IT], dsv[IT], sc[IT];
    int msk[IT];
    float be2v = be2[0];
    #pragma unroll
    for (int r = 0; r < IT; ++r) {
        float2 rp = rel2[(size_t)(b * NN + i0 + r) * NN + j];
        rx[r] = rp.x; ry[r] = rp.y;
        dsv[r] = sqrtf(rp.x * rp.x + rp.y * rp.y);
        msk[r] = adj[(size_t)(b * NN + i0 + r) * NN + j];
        sc[r] = be2v;
    }
    const float* TI = ti + (size_t)(b * NN + i0) * DD;      // uniform -> s_load
    const float* W0 = We1 + (size_t)(2 * DD + 0) * DD;
    const float* W1 = We1 + (size_t)(2 * DD + 1) * DD;
    const float* W2 = We1 + (size_t)(2 * DD + 2) * DD;
    const float* AJb = ajp + (size_t)b * NN * DD;

    for (int dc = 0; dc < DD; dc += 32) {
        __syncthreads();
        // stage aj[:, dc:dc+32]: XOR-swizzled float4 slots (conflict-optimal b128 r/w)
        #pragma unroll
        for (int it = 0; it < 8; ++it) {
            int idx = tid + it * 256;          // 0..2047 float4s
            int rr = idx >> 3, g = idx & 7;
            float4 v = *(const float4*)&AJb[(size_t)rr * DD + dc + (g << 2)];
            *(float4*)&s_buf[rr * 32 + ((g ^ (rr & 7)) << 2)] = v;
        }
        __syncthreads();
        #pragma unroll
        for (int g = 0; g < 8; ++g) {
            float4 a = *(const float4*)&s_buf[j * 32 + ((g ^ (j & 7)) << 2)];
            int dd = dc + (g << 2);
            float4 w0 = *(const float4*)&W0[dd];
            float4 w1 = *(const float4*)&W1[dd];
            float4 w2 = *(const float4*)&W2[dd];
            float4 e2 = *(const float4*)&We2[dd];
            #pragma unroll
            for (int r = 0; r < IT; ++r) {
                float4 t = *(const float4*)&TI[r * DD + dd];
                float v;
                v = fmaf(rx[r], w0.x, t.x + a.x); v = fmaf(ry[r], w1.x, v); v = fmaf(dsv[r], w2.x, v);
                sc[r] = fmaf(fmaxf(v, 0.f), e2.x, sc[r]);
                v = fmaf(rx[r], w0.y, t.y + a.y); v = fmaf(ry[r], w1.y, v); v = fmaf(dsv[r], w2.y, v);
                sc[r] = fmaf(fmaxf(v, 0.f), e2.y, sc[r]);
                v = fmaf(rx[r], w0.z, t.z + a.z); v = fmaf(ry[r], w1.z, v); v = fmaf(dsv[r], w2.z, v);
                sc[r] = fmaf(fmaxf(v, 0.f), e2.z, sc[r]);
                v = fmaf(rx[r], w0.w, t.w + a.w); v = fmaf(ry[r], w1.w, v); v = fmaf(dsv[r], w2.w, v);
                sc[r] = fmaf(fmaxf(v, 0.f), e2.w, sc[r]);
            }
        }
    }
    #pragma unroll
    for (int r = 0; r < IT; ++r) if (msk[r] == 0) sc[r] = -3.0e38f;

    // ---- Phase 2: masked softmax across j (4 waves)
    int wave = tid >> 6, lane = tid & 63;
    float e[IT];
    {
        float m[IT];
        #pragma unroll
        for (int r = 0; r < IT; ++r) m[r] = sc[r];
        for (int off = 32; off > 0; off >>= 1) {
            #pragma unroll
            for (int r = 0; r < IT; ++r) m[r] = fmaxf(m[r], __shfl_xor(m[r], off));
        }
        if (lane == 0) {
            #pragma unroll
            for (int r = 0; r < IT; ++r) s_red[r][wave] = m[r];
        }
    }
    __syncthreads();
    #pragma unroll
    for (int r = 0; r < IT; ++r) {
        float M = fmaxf(fmaxf(s_red[r][0], s_red[r][1]), fmaxf(s_red[r][2], s_red[r][3]));
        e[r] = (msk[r] == 0) ? 0.f : __expf(sc[r] - M);
    }
    __syncthreads();
    {
        float s[IT];
        #pragma unroll
        for (int r = 0; r < IT; ++r) s[r] = e[r];
        for (int off = 32; off > 0; off >>= 1) {
            #pragma unroll
            for (int r = 0; r < IT; ++r) s[r] += __shfl_xor(s[r], off);
        }
        if (lane == 0) {
            #pragma unroll
            for (int r = 0; r < IT; ++r) s_red[r][wave] = s[r];
        }
    }
    __syncthreads();
    {
        float4 wq;
        float S0 = s_red[0][0] + s_red[0][1] + s_red[0][2] + s_red[0][3];
        float S1 = s_red[1][0] + s_red[1][1] + s_red[1][2] + s_red[1][3];
        float S2 = s_red[2][0] + s_red[2][1] + s_red[2][2] + s_red[2][3];
        float S3 = s_red[3][0] + s_red[3][1] + s_red[3][2] + s_red[3][3];
        wq.x = e[0] * __builtin_amdgcn_rcpf(S0);
        wq.y = e[1] * __builtin_amdgcn_rcpf(S1);
        wq.z = e[2] * __builtin_amdgcn_rcpf(S2);
        wq.w = e[3] * __builtin_amdgcn_rcpf(S3);
        *(float4*)&s_w[j << 2] = wq;                   // transposed [j][r]
    }
    __syncthreads();

    // ---- Phase 3: msg = w@h via slice partials. Thread: g3=tid&31 (d4-group), sl=tid>>5 (j-slice)
    // s_part slot stride 20 floats: b128-aligned stores, 2-way (free) reduction reads.
    float* s_part = s_buf;
    int g3 = tid & 31, sl = tid >> 5;
    {
        const float* hb = h + (size_t)b * NN * DD;
        float4 acc[IT];
        #pragma unroll
        for (int r = 0; r < IT; ++r) acc[r] = make_float4(0.f, 0.f, 0.f, 0.f);
        for (int q = 0; q < 32; ++q) {
            int jj = (sl << 5) + q;
            float4 hv = *(const float4*)&hb[(size_t)jj * DD + (g3 << 2)];
            float4 wv = *(const float4*)&s_w[jj << 2];   // broadcast
            acc[0].x = fmaf(wv.x, hv.x, acc[0].x); acc[0].y = fmaf(wv.x, hv.y, acc[0].y);
            acc[0].z = fmaf(wv.x, hv.z, acc[0].z); acc[0].w = fmaf(wv.x, hv.w, acc[0].w);
            acc[1].x = fmaf(wv.y, hv.x, acc[1].x); acc[1].y = fmaf(wv.y, hv.y, acc[1].y);
            acc[1].z = fmaf(wv.y, hv.z, acc[1].z); acc[1].w = fmaf(wv.y, hv.w, acc[1].w);
            acc[2].x = fmaf(wv.z, hv.x, acc[2].x); acc[2].y = fmaf(wv.z, hv.y, acc[2].y);
            acc[2].z = fmaf(wv.z, hv.z, acc[2].z); acc[2].w = fmaf(wv.z, hv.w, acc[2].w);
            acc[3].x = fmaf(wv.w, hv.x, acc[3].x); acc[3].y = fmaf(wv.w, hv.y, acc[3].y);
            acc[3].z = fmaf(wv.w, hv.z, acc[3].z); acc[3].w = fmaf(wv.w, hv.w, acc[3].w);
        }
        int base = ((sl << 5) + g3) * 20;
        #pragma unroll
        for (int r = 0; r < IT; ++r) *(float4*)&s_part[base + (r << 2)] = acc[r];
    }
    __syncthreads();
    #pragma unroll
    for (int p = 0; p < 2; ++p) {
        int o = tid + (p << 8);
        int r = o >> 7, d = o & 127;
        float s = 0.f;
        #pragma unroll
        for (int s2 = 0; s2 < 8; ++s2)
            s += s_part[((s2 << 5) + (d >> 2)) * 20 + (r << 2) + (d & 3)];
        s_m[(d << 2) + r] = s;
    }
    __syncthreads();

    // ---- Phase 4: agg partials = msg@Wa. Thread: g3 (d4-group), sl (k-slice of 16)
    {
        float4 ac[IT];
        #pragma unroll
        for (int r = 0; r < IT; ++r) ac[r] = make_float4(0.f, 0.f, 0.f, 0.f);
        for (int q = 0; q < 16; ++q) {
            int k = (sl << 4) + q;
            float4 wa = *(const float4*)&Wa[(size_t)k * DD + (g3 << 2)];
            float4 mv = *(const float4*)&s_m[k << 2];    // broadcast
            ac[0].x = fmaf(mv.x, wa.x, ac[0].x); ac[0].y = fmaf(mv.x, wa.y, ac[0].y);
            ac[0].z = fmaf(mv.x, wa.z, ac[0].z); ac[0].w = fmaf(mv.x, wa.w, ac[0].w);
            ac[1].x = fmaf(mv.y, wa.x, ac[1].x); ac[1].y = fmaf(mv.y, wa.y, ac[1].y);
            ac[1].z = fmaf(mv.y, wa.z, ac[1].z); ac[1].w = fmaf(mv.y, wa.w, ac[1].w);
            ac[2].x = fmaf(mv.z, wa.x, ac[2].x); ac[2].y = fmaf(mv.z, wa.y, ac[2].y);
            ac[2].z = fmaf(mv.z, wa.z, ac[2].z); ac[2].w = fmaf(mv.z, wa.w, ac[2].w);
            ac[3].x = fmaf(mv.w, wa.x, ac[3].x); ac[3].y = fmaf(mv.w, wa.y, ac[3].y);
            ac[3].z = fmaf(mv.w, wa.z, ac[3].z); ac[3].w = fmaf(mv.w, wa.w, ac[3].w);
        }
        __syncthreads();                                 // phase-3 reduce reads of s_part done
        int base = ((sl << 5) + g3) * 20;
        #pragma unroll
        for (int r = 0; r < IT; ++r) *(float4*)&s_part[base + (r << 2)] = ac[r];
    }
    __syncthreads();

    // ---- Phase 5: reduce, bias+relu, residual, LayerNorm (2 outputs/thread: rows r, r+2)
    {
        int d = tid & 127;
        int wh = (tid >> 6) & 1;
        float bad = ba[d], gam = gamma[d], bet = beta[d];
        float xv[2];
        #pragma unroll
        for (int p = 0; p < 2; ++p) {
            int o = tid + (p << 8);
            int r = o >> 7;
            float agg = 0.f;
            #pragma unroll
            for (int s2 = 0; s2 < 8; ++s2)
                agg += s_part[((s2 << 5) + (d >> 2)) * 20 + (r << 2) + (d & 3)];
            float x = node[(size_t)(b * NN + i0 + r) * DD + d] + fmaxf(agg + bad, 0.f);
            xv[p] = x;
            float s1 = x, s2v = x * x;
            for (int off = 32; off > 0; off >>= 1) {
                s1 += __shfl_xor(s1, off);
                s2v += __shfl_xor(s2v, off);
            }
            if (lane == 0) { s_red2[r][wh][0] = s1; s_red2[r][wh][1] = s2v; }
        }
        __syncthreads();
        #pragma unroll
        for (int p = 0; p < 2; ++p) {
            int o = tid + (p << 8);
            int r = o >> 7;
            float t1 = s_red2[r][0][0] + s_red2[r][1][0];
            float t2 = s_red2[r][0][1] + s_red2[r][1][1];
            float mu  = t1 * (1.0f / DD);
            float var = t2 * (1.0f / DD) - mu * mu;
            float inv = rsqrtf(var + 1e-5f);
            out[(size_t)(b * NN + i0 + r) * DD + d] = (xv[p] - mu) * inv * gam + bet;
        }
    }
}

extern "C" void kernel_launch(void* const* d_in, const int* in_sizes, int n_in,
                              void* d_out, int out_size, void* d_ws, size_t ws_size,
                              hipStream_t stream) {
    const float* node = (const float*)d_in[0];
    const int*   adj  = (const int*)d_in[1];
    const float* rel  = (const float*)d_in[2];
    const float* Wn   = (const float*)d_in[3];
    const float* bn   = (const float*)d_in[4];
    const float* We1  = (const float*)d_in[5];
    const float* be1  = (const float*)d_in[6];
    const float* We2  = (const float*)d_in[7];
    const float* be2  = (const float*)d_in[8];
    const float* Wa   = (const float*)d_in[9];
    const float* ba   = (const float*)d_in[10];
    const float* gamma = (const float*)d_in[11];
    const float* beta  = (const float*)d_in[12];
    float* out = (float*)d_out;

    float* ws  = (float*)d_ws;
    const int ROWS = BB * NN * DD;          // 262144
    float* h   = ws;
    float* ti  = ws + ROWS;
    float* aj  = ws + 2 * ROWS;

    prep_kernel<<<BB * NN / PR, 256, 0, stream>>>(node, Wn, bn, We1, be1, h, ti, aj);
    edge_kernel<<<BB * NN / IT, 256, 0, stream>>>(ti, aj, rel, adj, We1, We2, be2,
                                                  h, Wa, ba, node, gamma, beta, out);
}

// Round 8
// 111.759 us; speedup vs baseline: 1.0996x; 1.0476x over previous
//
#include <hip/hip_runtime.h>
#include <math.h>

#define BB 8
#define NN 256
#define DD 128

typedef _Float16 h2 __attribute__((ext_vector_type(2)));
union U4 { uint4 u; float4 f; h2 h[8]; };

static __device__ __forceinline__ h2 relu2(h2 v) {
    h2 z = {(_Float16)0, (_Float16)0};
#if __has_builtin(__builtin_elementwise_max)
    return __builtin_elementwise_max(v, z);
#else
    v.x = v.x > z.x ? v.x : z.x;
    v.y = v.y > z.y ? v.y : z.y;
    return v;
#endif
}

static __device__ __forceinline__ float dot2acc(h2 a, h2 b, float c) {
#if __has_builtin(__builtin_amdgcn_fdot2)
    return __builtin_amdgcn_fdot2(a, b, c, false);
#else
    return fmaf((float)a.x, (float)b.x, fmaf((float)a.y, (float)b.y, c));
#endif
}

// ---------------- Kernel A: h = node@Wn+bn (f32), ti = node@We1[:D]+be1 (f16),
//                  aj = node@We1[D:2D] (f16). Block 0 also converts edge weights to f16.
#define PR 4
__global__ __launch_bounds__(256) void prep_kernel(
    const float* __restrict__ node, const float* __restrict__ Wn,
    const float* __restrict__ bn, const float* __restrict__ We1,
    const float* __restrict__ be1, const float* __restrict__ We2,
    float* __restrict__ h, _Float16* __restrict__ tih,
    _Float16* __restrict__ ajh, _Float16* __restrict__ wth)
{
    __shared__ __align__(16) float sx[PR * DD];
    __shared__ float s_acc[12 * 128];
    int tid = threadIdx.x;
    int cp = tid & 63;
    int rp = (tid >> 6) & 1;
    int ks = tid >> 7;
    int row0 = blockIdx.x * PR;
    if (tid < 128) {
        int rr = tid >> 5, cc = (tid & 31) << 2;
        *(float4*)&sx[rr * DD + cc] = *(const float4*)&node[(size_t)(row0 + rr) * DD + cc];
    }
    // block 0: convert edge-MLP rel-weights + We2 to f16 (wth rows: w0,w1,w2,e2)
    if (blockIdx.x == 0 && tid < 128) {
        wth[0 * 128 + tid] = (_Float16)We1[(size_t)(2 * DD + 0) * DD + tid];
        wth[1 * 128 + tid] = (_Float16)We1[(size_t)(2 * DD + 1) * DD + tid];
        wth[2 * 128 + tid] = (_Float16)We1[(size_t)(2 * DD + 2) * DD + tid];
        wth[3 * 128 + tid] = (_Float16)We2[tid];
    }
    __syncthreads();
    int d0 = cp << 1;
    int ra = rp << 1, rb = ra | 1;
    float ah[2] = {0.f, 0.f}, ai[2] = {0.f, 0.f}, ajc[2] = {0.f, 0.f};
    float bh[2] = {0.f, 0.f}, bi[2] = {0.f, 0.f}, bjc[2] = {0.f, 0.f};
    int k0 = ks << 6;
    for (int k = k0; k < k0 + 64; k += 4) {
        float4 xa = *(const float4*)&sx[ra * DD + k];
        float4 xb = *(const float4*)&sx[rb * DD + k];
        #pragma unroll
        for (int kk = 0; kk < 4; ++kk) {
            float2 w0 = *(const float2*)&Wn [(size_t)(k + kk) * DD + d0];
            float2 w1 = *(const float2*)&We1[(size_t)(k + kk) * DD + d0];
            float2 w2 = *(const float2*)&We1[(size_t)(DD + k + kk) * DD + d0];
            float xav = (kk == 0) ? xa.x : (kk == 1) ? xa.y : (kk == 2) ? xa.z : xa.w;
            float xbv = (kk == 0) ? xb.x : (kk == 1) ? xb.y : (kk == 2) ? xb.z : xb.w;
            ah[0] = fmaf(xav, w0.x, ah[0]); ah[1] = fmaf(xav, w0.y, ah[1]);
            ai[0] = fmaf(xav, w1.x, ai[0]); ai[1] = fmaf(xav, w1.y, ai[1]);
            ajc[0] = fmaf(xav, w2.x, ajc[0]); ajc[1] = fmaf(xav, w2.y, ajc[1]);
            bh[0] = fmaf(xbv, w0.x, bh[0]); bh[1] = fmaf(xbv, w0.y, bh[1]);
            bi[0] = fmaf(xbv, w1.x, bi[0]); bi[1] = fmaf(xbv, w1.y, bi[1]);
            bjc[0] = fmaf(xbv, w2.x, bjc[0]); bjc[1] = fmaf(xbv, w2.y, bjc[1]);
        }
    }
    int p = (rp << 6) | cp;
    if (ks == 1) {
        s_acc[0 * 128 + p] = ah[0];  s_acc[1 * 128 + p] = ah[1];
        s_acc[2 * 128 + p] = ai[0];  s_acc[3 * 128 + p] = ai[1];
        s_acc[4 * 128 + p] = ajc[0]; s_acc[5 * 128 + p] = ajc[1];
        s_acc[6 * 128 + p] = bh[0];  s_acc[7 * 128 + p] = bh[1];
        s_acc[8 * 128 + p] = bi[0];  s_acc[9 * 128 + p] = bi[1];
        s_acc[10 * 128 + p] = bjc[0]; s_acc[11 * 128 + p] = bjc[1];
    }
    __syncthreads();
    if (ks == 0) {
        float2 bn2  = *(const float2*)&bn[d0];
        float2 be12 = *(const float2*)&be1[d0];
        ah[0] += s_acc[0 * 128 + p] + bn2.x;  ah[1] += s_acc[1 * 128 + p] + bn2.y;
        ai[0] += s_acc[2 * 128 + p] + be12.x; ai[1] += s_acc[3 * 128 + p] + be12.y;
        ajc[0] += s_acc[4 * 128 + p];         ajc[1] += s_acc[5 * 128 + p];
        bh[0] += s_acc[6 * 128 + p] + bn2.x;  bh[1] += s_acc[7 * 128 + p] + bn2.y;
        bi[0] += s_acc[8 * 128 + p] + be12.x; bi[1] += s_acc[9 * 128 + p] + be12.y;
        bjc[0] += s_acc[10 * 128 + p];        bjc[1] += s_acc[11 * 128 + p];
        size_t oa = (size_t)(row0 + ra) * DD + d0;
        size_t ob = (size_t)(row0 + rb) * DD + d0;
        *(float2*)&h[oa] = make_float2(ah[0], ah[1]);
        *(float2*)&h[ob] = make_float2(bh[0], bh[1]);
        *(h2*)&tih[oa] = (h2){(_Float16)ai[0], (_Float16)ai[1]};
        *(h2*)&tih[ob] = (h2){(_Float16)bi[0], (_Float16)bi[1]};
        *(h2*)&ajh[oa] = (h2){(_Float16)ajc[0], (_Float16)ajc[1]};
        *(h2*)&ajh[ob] = (h2){(_Float16)bjc[0], (_Float16)bjc[1]};
    }
}

// ---------------- Kernel B (fused): f16 packed scores + softmax + msg=w@h + relu(msg@Wa+ba)
//                  + residual + LN. IT=4 rows/block, 256 threads, grid 512.
#define IT 4
__global__ __launch_bounds__(256, 2) void edge_kernel(
    const _Float16* __restrict__ tih, const _Float16* __restrict__ ajh,
    const _Float16* __restrict__ wth, const float* __restrict__ rel,
    const int* __restrict__ adj, const float* __restrict__ be2,
    const float* __restrict__ h, const float* __restrict__ Wa,
    const float* __restrict__ ba, const float* __restrict__ node,
    const float* __restrict__ gamma, const float* __restrict__ beta,
    float* __restrict__ out)
{
    __shared__ __align__(16) float s_buf[NN * 32];  // 32 KB: f16 aj chunks (phase 1), partials (3/4)
    __shared__ __align__(16) float s_w[NN * 4];     // w transposed: [j][r]
    __shared__ __align__(16) float s_m[DD * 4];     // msg transposed: [k][r]
    __shared__ float s_red[IT][4];
    __shared__ float s_red2[IT][2][2];

    int tid = threadIdx.x;
    int b  = blockIdx.x >> 6;
    int i0 = (blockIdx.x & 63) << 2;
    int j = tid;

    // ---- Phase 1: edge scores for 4 rows (packed f16); lane owns column j
    const float2* rel2 = (const float2*)rel;
    float sc[IT];
    int msk[IT];
    h2 rxh[IT], ryh[IT], dsh[IT];
    float be2v = be2[0];
    #pragma unroll
    for (int r = 0; r < IT; ++r) {
        float2 rp = rel2[(size_t)(b * NN + i0 + r) * NN + j];
        float ds = sqrtf(rp.x * rp.x + rp.y * rp.y);
        _Float16 xh = (_Float16)rp.x, yh = (_Float16)rp.y, dh = (_Float16)ds;
        rxh[r] = (h2){xh, xh}; ryh[r] = (h2){yh, yh}; dsh[r] = (h2){dh, dh};
        msk[r] = adj[(size_t)(b * NN + i0 + r) * NN + j];
        sc[r] = be2v;
    }
    const _Float16* TIH = tih + (size_t)(b * NN + i0) * DD;   // uniform base
    const _Float16* AJH = ajh + (size_t)b * NN * DD;

    for (int dc = 0; dc < DD; dc += 64) {
        __syncthreads();
        // stage f16 aj[:, dc:dc+64]: rows of 128B, XOR-swizzled 16B granules
        #pragma unroll
        for (int it = 0; it < 8; ++it) {
            int idx = tid + it * 256;          // 0..2047 granules
            int rr = idx >> 3, g = idx & 7;
            float4 v = *(const float4*)&AJH[(size_t)rr * DD + dc + (g << 3)];
            *(float4*)&s_buf[rr * 32 + ((g ^ (rr & 7)) << 2)] = v;
        }
        __syncthreads();
        #pragma unroll
        for (int gg = 0; gg < 8; ++gg) {
            U4 a; a.f = *(const float4*)&s_buf[j * 32 + ((gg ^ (j & 7)) << 2)];
            int dd = dc + (gg << 3);
            U4 w0u, w1u, w2u, e2u;
            w0u.u = *(const uint4*)&wth[0 * 128 + dd];
            w1u.u = *(const uint4*)&wth[1 * 128 + dd];
            w2u.u = *(const uint4*)&wth[2 * 128 + dd];
            e2u.u = *(const uint4*)&wth[3 * 128 + dd];
            #pragma unroll
            for (int r = 0; r < IT; ++r) {
                U4 t; t.u = *(const uint4*)&TIH[r * DD + dd];
                #pragma unroll
                for (int u = 0; u < 4; ++u) {
                    h2 v = t.h[u] + a.h[u];
                    v = rxh[r] * w0u.h[u] + v;
                    v = ryh[r] * w1u.h[u] + v;
                    v = dsh[r] * w2u.h[u] + v;
                    v = relu2(v);
                    sc[r] = dot2acc(v, e2u.h[u], sc[r]);
                }
            }
        }
    }
    #pragma unroll
    for (int r = 0; r < IT; ++r) if (msk[r] == 0) sc[r] = -3.0e38f;

    // ---- Phase 2: masked softmax across j (4 waves)
    int wave = tid >> 6, lane = tid & 63;
    float e[IT];
    {
        float m[IT];
        #pragma unroll
        for (int r = 0; r < IT; ++r) m[r] = sc[r];
        for (int off = 32; off > 0; off >>= 1) {
            #pragma unroll
            for (int r = 0; r < IT; ++r) m[r] = fmaxf(m[r], __shfl_xor(m[r], off));
        }
        if (lane == 0) {
            #pragma unroll
            for (int r = 0; r < IT; ++r) s_red[r][wave] = m[r];
        }
    }
    __syncthreads();
    #pragma unroll
    for (int r = 0; r < IT; ++r) {
        float M = fmaxf(fmaxf(s_red[r][0], s_red[r][1]), fmaxf(s_red[r][2], s_red[r][3]));
        e[r] = (msk[r] == 0) ? 0.f : __expf(sc[r] - M);
    }
    __syncthreads();
    {
        float s[IT];
        #pragma unroll
        for (int r = 0; r < IT; ++r) s[r] = e[r];
        for (int off = 32; off > 0; off >>= 1) {
            #pragma unroll
            for (int r = 0; r < IT; ++r) s[r] += __shfl_xor(s[r], off);
        }
        if (lane == 0) {
            #pragma unroll
            for (int r = 0; r < IT; ++r) s_red[r][wave] = s[r];
        }
    }
    __syncthreads();
    {
        float4 wq;
        float S0 = s_red[0][0] + s_red[0][1] + s_red[0][2] + s_red[0][3];
        float S1 = s_red[1][0] + s_red[1][1] + s_red[1][2] + s_red[1][3];
        float S2 = s_red[2][0] + s_red[2][1] + s_red[2][2] + s_red[2][3];
        float S3 = s_red[3][0] + s_red[3][1] + s_red[3][2] + s_red[3][3];
        wq.x = e[0] * __builtin_amdgcn_rcpf(S0);
        wq.y = e[1] * __builtin_amdgcn_rcpf(S1);
        wq.z = e[2] * __builtin_amdgcn_rcpf(S2);
        wq.w = e[3] * __builtin_amdgcn_rcpf(S3);
        *(float4*)&s_w[j << 2] = wq;
    }
    __syncthreads();

    // ---- Phase 3: msg = w@h via slice partials (f32). Thread: g3=tid&31, sl=tid>>5
    float* s_part = s_buf;
    int g3 = tid & 31, sl = tid >> 5;
    {
        const float* hb = h + (size_t)b * NN * DD;
        float4 acc[IT];
        #pragma unroll
        for (int r = 0; r < IT; ++r) acc[r] = make_float4(0.f, 0.f, 0.f, 0.f);
        for (int q = 0; q < 32; ++q) {
            int jj = (sl << 5) + q;
            float4 hv = *(const float4*)&hb[(size_t)jj * DD + (g3 << 2)];
            float4 wv = *(const float4*)&s_w[jj << 2];
            acc[0].x = fmaf(wv.x, hv.x, acc[0].x); acc[0].y = fmaf(wv.x, hv.y, acc[0].y);
            acc[0].z = fmaf(wv.x, hv.z, acc[0].z); acc[0].w = fmaf(wv.x, hv.w, acc[0].w);
            acc[1].x = fmaf(wv.y, hv.x, acc[1].x); acc[1].y = fmaf(wv.y, hv.y, acc[1].y);
            acc[1].z = fmaf(wv.y, hv.z, acc[1].z); acc[1].w = fmaf(wv.y, hv.w, acc[1].w);
            acc[2].x = fmaf(wv.z, hv.x, acc[2].x); acc[2].y = fmaf(wv.z, hv.y, acc[2].y);
            acc[2].z = fmaf(wv.z, hv.z, acc[2].z); acc[2].w = fmaf(wv.z, hv.w, acc[2].w);
            acc[3].x = fmaf(wv.w, hv.x, acc[3].x); acc[3].y = fmaf(wv.w, hv.y, acc[3].y);
            acc[3].z = fmaf(wv.w, hv.z, acc[3].z); acc[3].w = fmaf(wv.w, hv.w, acc[3].w);
        }
        int base = ((sl << 5) + g3) * 20;
        #pragma unroll
        for (int r = 0; r < IT; ++r) *(float4*)&s_part[base + (r << 2)] = acc[r];
    }
    __syncthreads();
    #pragma unroll
    for (int p = 0; p < 2; ++p) {
        int o = tid + (p << 8);
        int r = o >> 7, d = o & 127;
        float s = 0.f;
        #pragma unroll
        for (int s2 = 0; s2 < 8; ++s2)
            s += s_part[((s2 << 5) + (d >> 2)) * 20 + (r << 2) + (d & 3)];
        s_m[(d << 2) + r] = s;
    }
    __syncthreads();

    // ---- Phase 4: agg partials = msg@Wa
    {
        float4 ac[IT];
        #pragma unroll
        for (int r = 0; r < IT; ++r) ac[r] = make_float4(0.f, 0.f, 0.f, 0.f);
        for (int q = 0; q < 16; ++q) {
            int k = (sl << 4) + q;
            float4 wa = *(const float4*)&Wa[(size_t)k * DD + (g3 << 2)];
            float4 mv = *(const float4*)&s_m[k << 2];
            ac[0].x = fmaf(mv.x, wa.x, ac[0].x); ac[0].y = fmaf(mv.x, wa.y, ac[0].y);
            ac[0].z = fmaf(mv.x, wa.z, ac[0].z); ac[0].w = fmaf(mv.x, wa.w, ac[0].w);
            ac[1].x = fmaf(mv.y, wa.x, ac[1].x); ac[1].y = fmaf(mv.y, wa.y, ac[1].y);
            ac[1].z = fmaf(mv.y, wa.z, ac[1].z); ac[1].w = fmaf(mv.y, wa.w, ac[1].w);
            ac[2].x = fmaf(mv.z, wa.x, ac[2].x); ac[2].y = fmaf(mv.z, wa.y, ac[2].y);
            ac[2].z = fmaf(mv.z, wa.z, ac[2].z); ac[2].w = fmaf(mv.z, wa.w, ac[2].w);
            ac[3].x = fmaf(mv.w, wa.x, ac[3].x); ac[3].y = fmaf(mv.w, wa.y, ac[3].y);
            ac[3].z = fmaf(mv.w, wa.z, ac[3].z); ac[3].w = fmaf(mv.w, wa.w, ac[3].w);
        }
        __syncthreads();
        int base = ((sl << 5) + g3) * 20;
        #pragma unroll
        for (int r = 0; r < IT; ++r) *(float4*)&s_part[base + (r << 2)] = ac[r];
    }
    __syncthreads();

    // ---- Phase 5: reduce, bias+relu, residual, LayerNorm
    {
        int d = tid & 127;
        int wh = (tid >> 6) & 1;
        float bad = ba[d], gam = gamma[d], bet = beta[d];
        float xv[2];
        #pragma unroll
        for (int p = 0; p < 2; ++p) {
            int o = tid + (p << 8);
            int r = o >> 7;
            float agg = 0.f;
            #pragma unroll
            for (int s2 = 0; s2 < 8; ++s2)
                agg += s_part[((s2 << 5) + (d >> 2)) * 20 + (r << 2) + (d & 3)];
            float x = node[(size_t)(b * NN + i0 + r) * DD + d] + fmaxf(agg + bad, 0.f);
            xv[p] = x;
            float s1 = x, s2v = x * x;
            for (int off = 32; off > 0; off >>= 1) {
                s1 += __shfl_xor(s1, off);
                s2v += __shfl_xor(s2v, off);
            }
            if (lane == 0) { s_red2[r][wh][0] = s1; s_red2[r][wh][1] = s2v; }
        }
        __syncthreads();
        #pragma unroll
        for (int p = 0; p < 2; ++p) {
            int o = tid + (p << 8);
            int r = o >> 7;
            float t1 = s_red2[r][0][0] + s_red2[r][1][0];
            float t2 = s_red2[r][0][1] + s_red2[r][1][1];
            float mu  = t1 * (1.0f / DD);
            float var = t2 * (1.0f / DD) - mu * mu;
            float inv = rsqrtf(var + 1e-5f);
            out[(size_t)(b * NN + i0 + r) * DD + d] = (xv[p] - mu) * inv * gam + bet;
        }
    }
}

extern "C" void kernel_launch(void* const* d_in, const int* in_sizes, int n_in,
                              void* d_out, int out_size, void* d_ws, size_t ws_size,
                              hipStream_t stream) {
    const float* node = (const float*)d_in[0];
    const int*   adj  = (const int*)d_in[1];
    const float* rel  = (const float*)d_in[2];
    const float* Wn   = (const float*)d_in[3];
    const float* bn   = (const float*)d_in[4];
    const float* We1  = (const float*)d_in[5];
    const float* be1  = (const float*)d_in[6];
    const float* We2  = (const float*)d_in[7];
    const float* be2  = (const float*)d_in[8];
    const float* Wa   = (const float*)d_in[9];
    const float* ba   = (const float*)d_in[10];
    const float* gamma = (const float*)d_in[11];
    const float* beta  = (const float*)d_in[12];
    float* out = (float*)d_out;

    float* ws  = (float*)d_ws;
    const int ROWS = BB * NN * DD;              // 262144
    float* h        = ws;                       // f32
    _Float16* tih   = (_Float16*)(ws + ROWS);   // f16, ROWS halfs
    _Float16* ajh   = tih + ROWS;               // f16, ROWS halfs
    _Float16* wth   = ajh + ROWS;               // f16, 512 halfs

    prep_kernel<<<BB * NN / PR, 256, 0, stream>>>(node, Wn, bn, We1, be1, We2,
                                                  h, tih, ajh, wth);
    edge_kernel<<<BB * NN / IT, 256, 0, stream>>>(tih, ajh, wth, rel, adj, be2,
                                                  h, Wa, ba, node, gamma, beta, out);
}

// Round 9
// 110.538 us; speedup vs baseline: 1.1118x; 1.0110x over previous
//
#include <hip/hip_runtime.h>
#include <math.h>

#define BB 8
#define NN 256
#define DD 128

typedef _Float16 h2 __attribute__((ext_vector_type(2)));
union U4 { uint4 u; float4 f; h2 h[8]; };

static __device__ __forceinline__ h2 relu2(h2 v) {
    h2 z = {(_Float16)0, (_Float16)0};
#if __has_builtin(__builtin_elementwise_max)
    return __builtin_elementwise_max(v, z);
#else
    v.x = v.x > z.x ? v.x : z.x;
    v.y = v.y > z.y ? v.y : z.y;
    return v;
#endif
}

static __device__ __forceinline__ float dot2acc(h2 a, h2 b, float c) {
#if __has_builtin(__builtin_amdgcn_fdot2)
    return __builtin_amdgcn_fdot2(a, b, c, false);
#else
    return fmaf((float)a.x, (float)b.x, fmaf((float)a.y, (float)b.y, c));
#endif
}

// ---------------- Kernel A: h = node@Wn+bn (f32), ti = node@We1[:D]+be1 (f16),
//                  aj = node@We1[D:2D] (f16). Block 0 also converts edge weights to f16.
#define PR 4
__global__ __launch_bounds__(256) void prep_kernel(
    const float* __restrict__ node, const float* __restrict__ Wn,
    const float* __restrict__ bn, const float* __restrict__ We1,
    const float* __restrict__ be1, const float* __restrict__ We2,
    float* __restrict__ h, _Float16* __restrict__ tih,
    _Float16* __restrict__ ajh, _Float16* __restrict__ wth)
{
    __shared__ __align__(16) float sx[PR * DD];
    __shared__ float s_acc[12 * 128];
    int tid = threadIdx.x;
    int cp = tid & 63;
    int rp = (tid >> 6) & 1;
    int ks = tid >> 7;
    int row0 = blockIdx.x * PR;
    if (tid < 128) {
        int rr = tid >> 5, cc = (tid & 31) << 2;
        *(float4*)&sx[rr * DD + cc] = *(const float4*)&node[(size_t)(row0 + rr) * DD + cc];
    }
    if (blockIdx.x == 0 && tid < 128) {
        wth[0 * 128 + tid] = (_Float16)We1[(size_t)(2 * DD + 0) * DD + tid];
        wth[1 * 128 + tid] = (_Float16)We1[(size_t)(2 * DD + 1) * DD + tid];
        wth[2 * 128 + tid] = (_Float16)We1[(size_t)(2 * DD + 2) * DD + tid];
        wth[3 * 128 + tid] = (_Float16)We2[tid];
    }
    __syncthreads();
    int d0 = cp << 1;
    int ra = rp << 1, rb = ra | 1;
    float ah[2] = {0.f, 0.f}, ai[2] = {0.f, 0.f}, ajc[2] = {0.f, 0.f};
    float bh[2] = {0.f, 0.f}, bi[2] = {0.f, 0.f}, bjc[2] = {0.f, 0.f};
    int k0 = ks << 6;
    for (int k = k0; k < k0 + 64; k += 4) {
        float4 xa = *(const float4*)&sx[ra * DD + k];
        float4 xb = *(const float4*)&sx[rb * DD + k];
        #pragma unroll
        for (int kk = 0; kk < 4; ++kk) {
            float2 w0 = *(const float2*)&Wn [(size_t)(k + kk) * DD + d0];
            float2 w1 = *(const float2*)&We1[(size_t)(k + kk) * DD + d0];
            float2 w2 = *(const float2*)&We1[(size_t)(DD + k + kk) * DD + d0];
            float xav = (kk == 0) ? xa.x : (kk == 1) ? xa.y : (kk == 2) ? xa.z : xa.w;
            float xbv = (kk == 0) ? xb.x : (kk == 1) ? xb.y : (kk == 2) ? xb.z : xb.w;
            ah[0] = fmaf(xav, w0.x, ah[0]); ah[1] = fmaf(xav, w0.y, ah[1]);
            ai[0] = fmaf(xav, w1.x, ai[0]); ai[1] = fmaf(xav, w1.y, ai[1]);
            ajc[0] = fmaf(xav, w2.x, ajc[0]); ajc[1] = fmaf(xav, w2.y, ajc[1]);
            bh[0] = fmaf(xbv, w0.x, bh[0]); bh[1] = fmaf(xbv, w0.y, bh[1]);
            bi[0] = fmaf(xbv, w1.x, bi[0]); bi[1] = fmaf(xbv, w1.y, bi[1]);
            bjc[0] = fmaf(xbv, w2.x, bjc[0]); bjc[1] = fmaf(xbv, w2.y, bjc[1]);
        }
    }
    int p = (rp << 6) | cp;
    if (ks == 1) {
        s_acc[0 * 128 + p] = ah[0];  s_acc[1 * 128 + p] = ah[1];
        s_acc[2 * 128 + p] = ai[0];  s_acc[3 * 128 + p] = ai[1];
        s_acc[4 * 128 + p] = ajc[0]; s_acc[5 * 128 + p] = ajc[1];
        s_acc[6 * 128 + p] = bh[0];  s_acc[7 * 128 + p] = bh[1];
        s_acc[8 * 128 + p] = bi[0];  s_acc[9 * 128 + p] = bi[1];
        s_acc[10 * 128 + p] = bjc[0]; s_acc[11 * 128 + p] = bjc[1];
    }
    __syncthreads();
    if (ks == 0) {
        float2 bn2  = *(const float2*)&bn[d0];
        float2 be12 = *(const float2*)&be1[d0];
        ah[0] += s_acc[0 * 128 + p] + bn2.x;  ah[1] += s_acc[1 * 128 + p] + bn2.y;
        ai[0] += s_acc[2 * 128 + p] + be12.x; ai[1] += s_acc[3 * 128 + p] + be12.y;
        ajc[0] += s_acc[4 * 128 + p];         ajc[1] += s_acc[5 * 128 + p];
        bh[0] += s_acc[6 * 128 + p] + bn2.x;  bh[1] += s_acc[7 * 128 + p] + bn2.y;
        bi[0] += s_acc[8 * 128 + p] + be12.x; bi[1] += s_acc[9 * 128 + p] + be12.y;
        bjc[0] += s_acc[10 * 128 + p];        bjc[1] += s_acc[11 * 128 + p];
        size_t oa = (size_t)(row0 + ra) * DD + d0;
        size_t ob = (size_t)(row0 + rb) * DD + d0;
        *(float2*)&h[oa] = make_float2(ah[0], ah[1]);
        *(float2*)&h[ob] = make_float2(bh[0], bh[1]);
        *(h2*)&tih[oa] = (h2){(_Float16)ai[0], (_Float16)ai[1]};
        *(h2*)&tih[ob] = (h2){(_Float16)bi[0], (_Float16)bi[1]};
        *(h2*)&ajh[oa] = (h2){(_Float16)ajc[0], (_Float16)ajc[1]};
        *(h2*)&ajh[ob] = (h2){(_Float16)bjc[0], (_Float16)bjc[1]};
    }
}

// ---------------- Kernel B (fused): IT=8 rows/block, 512 threads, grid 256 (1 block/CU).
// Full 64KB f16 aj tile staged once; thread = (j = tid&255, half = tid>>8 -> rows 4h..4h+3).
#define IT 8
__global__ __launch_bounds__(512, 2) void edge_kernel(
    const _Float16* __restrict__ tih, const _Float16* __restrict__ ajh,
    const _Float16* __restrict__ wth, const float* __restrict__ rel,
    const int* __restrict__ adj, const float* __restrict__ be2,
    const float* __restrict__ h, const float* __restrict__ Wa,
    const float* __restrict__ ba, const float* __restrict__ node,
    const float* __restrict__ gamma, const float* __restrict__ beta,
    float* __restrict__ out)
{
    __shared__ __align__(16) float s_buf[18432];   // 72KB: f16 tile (16K f) / partial slots (18K f)
    __shared__ __align__(16) float s_w[NN * 8];    // w transposed: [j][r], 8KB
    __shared__ __align__(16) float s_m[DD * 8];    // msg transposed: [k][r], 4KB
    __shared__ float s_redM[IT][4];
    __shared__ float s_redS[IT][4];
    __shared__ float s_red2[IT][2][2];

    int tid = threadIdx.x;
    int b  = blockIdx.x >> 5;                 // 32 blocks per batch
    int i0 = (blockIdx.x & 31) << 3;          // 8 rows
    int j    = tid & 255;
    int half = tid >> 8;                      // 0/1: rows 4*half .. 4*half+3
    int rb   = half << 2;

    // ---- per-thread edge inputs for 4 rows
    const float2* rel2 = (const float2*)rel;
    float sc[4];
    int msk[4];
    h2 rxh[4], ryh[4], dsh[4];
    float be2v = be2[0];
    #pragma unroll
    for (int r = 0; r < 4; ++r) {
        float2 rp = rel2[(size_t)(b * NN + i0 + rb + r) * NN + j];
        float ds = sqrtf(rp.x * rp.x + rp.y * rp.y);
        _Float16 xh = (_Float16)rp.x, yh = (_Float16)rp.y, dh = (_Float16)ds;
        rxh[r] = (h2){xh, xh}; ryh[r] = (h2){yh, yh}; dsh[r] = (h2){dh, dh};
        msk[r] = adj[(size_t)(b * NN + i0 + rb + r) * NN + j];
        sc[r] = be2v;
    }

    // ---- stage full f16 aj tile (256 rows x 128 f16 = 64KB), XOR-swizzled 16B granules
    {
        const _Float16* AJH = ajh + (size_t)b * NN * DD;
        #pragma unroll
        for (int it = 0; it < 8; ++it) {
            int idx = tid + (it << 9);         // 0..4095 granules
            int rr = idx >> 4, g = idx & 15;
            float4 v = *(const float4*)&AJH[(size_t)rr * DD + (g << 3)];
            *(float4*)&s_buf[rr * 64 + ((g ^ (rr & 15)) << 2)] = v;
        }
    }
    // wave-uniform ti base -> scalar loads
    int tibase = __builtin_amdgcn_readfirstlane((b * NN + i0 + rb) * DD);
    const _Float16* TIH = tih + tibase;
    __syncthreads();

    // ---- Phase 1: scores (packed f16)
    #pragma unroll 4
    for (int gg = 0; gg < 16; ++gg) {
        U4 a; a.f = *(const float4*)&s_buf[j * 64 + ((gg ^ (j & 15)) << 2)];
        int dd = gg << 3;
        U4 w0u, w1u, w2u, e2u;
        w0u.u = *(const uint4*)&wth[0 * 128 + dd];
        w1u.u = *(const uint4*)&wth[1 * 128 + dd];
        w2u.u = *(const uint4*)&wth[2 * 128 + dd];
        e2u.u = *(const uint4*)&wth[3 * 128 + dd];
        #pragma unroll
        for (int r = 0; r < 4; ++r) {
            U4 t; t.u = *(const uint4*)&TIH[r * DD + dd];
            #pragma unroll
            for (int u = 0; u < 4; ++u) {
                h2 v = t.h[u] + a.h[u];
                v = rxh[r] * w0u.h[u] + v;
                v = ryh[r] * w1u.h[u] + v;
                v = dsh[r] * w2u.h[u] + v;
                v = relu2(v);
                sc[r] = dot2acc(v, e2u.h[u], sc[r]);
            }
        }
    }
    #pragma unroll
    for (int r = 0; r < 4; ++r) if (msk[r] == 0) sc[r] = -3.0e38f;

    // ---- Phase 2: masked softmax across j (4 waves per half)
    int wave = tid >> 6, wig = wave & 3, lane = tid & 63;
    float e[4];
    {
        float m[4];
        #pragma unroll
        for (int r = 0; r < 4; ++r) m[r] = sc[r];
        for (int off = 32; off > 0; off >>= 1) {
            #pragma unroll
            for (int r = 0; r < 4; ++r) m[r] = fmaxf(m[r], __shfl_xor(m[r], off));
        }
        if (lane == 0) {
            #pragma unroll
            for (int r = 0; r < 4; ++r) s_redM[rb + r][wig] = m[r];
        }
    }
    __syncthreads();                              // B1: maxes ready
    {
        float s[4];
        #pragma unroll
        for (int r = 0; r < 4; ++r) {
            float M = fmaxf(fmaxf(s_redM[rb + r][0], s_redM[rb + r][1]),
                            fmaxf(s_redM[rb + r][2], s_redM[rb + r][3]));
            e[r] = (msk[r] == 0) ? 0.f : __expf(sc[r] - M);
            s[r] = e[r];
        }
        for (int off = 32; off > 0; off >>= 1) {
            #pragma unroll
            for (int r = 0; r < 4; ++r) s[r] += __shfl_xor(s[r], off);
        }
        if (lane == 0) {
            #pragma unroll
            for (int r = 0; r < 4; ++r) s_redS[rb + r][wig] = s[r];
        }
    }
    __syncthreads();                              // B2: sums ready
    {
        float4 wq;
        #pragma unroll
        for (int r = 0; r < 4; ++r) {
            float S = s_redS[rb + r][0] + s_redS[rb + r][1] + s_redS[rb + r][2] + s_redS[rb + r][3];
            float wv = e[r] * __builtin_amdgcn_rcpf(S);
            ((float*)&wq)[r] = wv;
        }
        *(float4*)&s_w[(j << 3) + rb] = wq;       // [j][8 rows]
    }
    __syncthreads();                              // B3: s_w ready; tile dead (s_part alias safe)

    // ---- Phase 3: msg partials = w@h. Thread: g3=tid&31 (d4-group), sl=tid>>5 (16 j-slices of 16)
    float* s_part = s_buf;                        // stride-36 slots
    int g3 = tid & 31, sl = tid >> 5;
    {
        const float* hb = h + (size_t)b * NN * DD;
        float4 acc[8];
        #pragma unroll
        for (int r = 0; r < 8; ++r) acc[r] = make_float4(0.f, 0.f, 0.f, 0.f);
        for (int q = 0; q < 16; ++q) {
            int jj = (sl << 4) + q;
            float4 hv = *(const float4*)&hb[(size_t)jj * DD + (g3 << 2)];
            float4 wa = *(const float4*)&s_w[(jj << 3) + 0];   // rows 0-3 (broadcast)
            float4 wb = *(const float4*)&s_w[(jj << 3) + 4];   // rows 4-7
            #pragma unroll
            for (int r = 0; r < 4; ++r) {
                float wv = ((float*)&wa)[r];
                acc[r].x = fmaf(wv, hv.x, acc[r].x); acc[r].y = fmaf(wv, hv.y, acc[r].y);
                acc[r].z = fmaf(wv, hv.z, acc[r].z); acc[r].w = fmaf(wv, hv.w, acc[r].w);
            }
            #pragma unroll
            for (int r = 0; r < 4; ++r) {
                float wv = ((float*)&wb)[r];
                acc[4 + r].x = fmaf(wv, hv.x, acc[4 + r].x); acc[4 + r].y = fmaf(wv, hv.y, acc[4 + r].y);
                acc[4 + r].z = fmaf(wv, hv.z, acc[4 + r].z); acc[4 + r].w = fmaf(wv, hv.w, acc[4 + r].w);
            }
        }
        int base = ((sl << 5) + g3) * 36;
        #pragma unroll
        for (int r = 0; r < 8; ++r) *(float4*)&s_part[base + (r << 2)] = acc[r];
    }
    __syncthreads();                              // B4: partials ready
    #pragma unroll
    for (int p = 0; p < 2; ++p) {
        int o = tid + (p << 9);
        int r = o >> 7, d = o & 127;
        float s = 0.f;
        #pragma unroll
        for (int s2 = 0; s2 < 16; ++s2)
            s += s_part[((s2 << 5) + (d >> 2)) * 36 + (r << 2) + (d & 3)];
        s_m[(d << 3) + r] = s;
    }
    __syncthreads();                              // B5: s_m ready; s_part reads done

    // ---- Phase 4: agg partials = msg@Wa. Thread: g3 (d4-group), sl (16 k-slices of 8)
    {
        float4 ac[8];
        #pragma unroll
        for (int r = 0; r < 8; ++r) ac[r] = make_float4(0.f, 0.f, 0.f, 0.f);
        for (int q = 0; q < 8; ++q) {
            int k = (sl << 3) + q;
            float4 wv = *(const float4*)&Wa[(size_t)k * DD + (g3 << 2)];
            float4 ma = *(const float4*)&s_m[(k << 3) + 0];
            float4 mb = *(const float4*)&s_m[(k << 3) + 4];
            #pragma unroll
            for (int r = 0; r < 4; ++r) {
                float mv = ((float*)&ma)[r];
                ac[r].x = fmaf(mv, wv.x, ac[r].x); ac[r].y = fmaf(mv, wv.y, ac[r].y);
                ac[r].z = fmaf(mv, wv.z, ac[r].z); ac[r].w = fmaf(mv, wv.w, ac[r].w);
            }
            #pragma unroll
            for (int r = 0; r < 4; ++r) {
                float mv = ((float*)&mb)[r];
                ac[4 + r].x = fmaf(mv, wv.x, ac[4 + r].x); ac[4 + r].y = fmaf(mv, wv.y, ac[4 + r].y);
                ac[4 + r].z = fmaf(mv, wv.z, ac[4 + r].z); ac[4 + r].w = fmaf(mv, wv.w, ac[4 + r].w);
            }
        }
        int base = ((sl << 5) + g3) * 36;
        #pragma unroll
        for (int r = 0; r < 8; ++r) *(float4*)&s_part[base + (r << 2)] = ac[r];
    }
    __syncthreads();                              // B6: agg partials ready

    // ---- Phase 5: reduce, bias+relu, residual, LayerNorm
    {
        int wh = wave & 1;                        // wave within the 2-wave row group
        float xv[2];
        int dref = tid & 127;
        float bad = ba[dref], gam = gamma[dref], bet = beta[dref];
        #pragma unroll
        for (int p = 0; p < 2; ++p) {
            int o = tid + (p << 9);
            int r = o >> 7, d = o & 127;
            float agg = 0.f;
            #pragma unroll
            for (int s2 = 0; s2 < 16; ++s2)
                agg += s_part[((s2 << 5) + (d >> 2)) * 36 + (r << 2) + (d & 3)];
            float x = node[(size_t)(b * NN + i0 + r) * DD + d] + fmaxf(agg + bad, 0.f);
            xv[p] = x;
            float s1 = x, s2v = x * x;
            for (int off = 32; off > 0; off >>= 1) {
                s1 += __shfl_xor(s1, off);
                s2v += __shfl_xor(s2v, off);
            }
            if (lane == 0) { s_red2[r][wh][0] = s1; s_red2[r][wh][1] = s2v; }
        }
        __syncthreads();                          // B7: LN stats ready
        #pragma unroll
        for (int p = 0; p < 2; ++p) {
            int o = tid + (p << 9);
            int r = o >> 7, d = o & 127;
            float t1 = s_red2[r][0][0] + s_red2[r][1][0];
            float t2 = s_red2[r][0][1] + s_red2[r][1][1];
            float mu  = t1 * (1.0f / DD);
            float var = t2 * (1.0f / DD) - mu * mu;
            float inv = rsqrtf(var + 1e-5f);
            out[(size_t)(b * NN + i0 + r) * DD + d] = (xv[p] - mu) * inv * gam + bet;
        }
    }
}

extern "C" void kernel_launch(void* const* d_in, const int* in_sizes, int n_in,
                              void* d_out, int out_size, void* d_ws, size_t ws_size,
                              hipStream_t stream) {
    const float* node = (const float*)d_in[0];
    const int*   adj  = (const int*)d_in[1];
    const float* rel  = (const float*)d_in[2];
    const float* Wn   = (const float*)d_in[3];
    const float* bn   = (const float*)d_in[4];
    const float* We1  = (const float*)d_in[5];
    const float* be1  = (const float*)d_in[6];
    const float* We2  = (const float*)d_in[7];
    const float* be2  = (const float*)d_in[8];
    const float* Wa   = (const float*)d_in[9];
    const float* ba   = (const float*)d_in[10];
    const float* gamma = (const float*)d_in[11];
    const float* beta  = (const float*)d_in[12];
    float* out = (float*)d_out;

    float* ws  = (float*)d_ws;
    const int ROWS = BB * NN * DD;              // 262144
    float* h        = ws;                       // f32
    _Float16* tih   = (_Float16*)(ws + ROWS);   // f16
    _Float16* ajh   = tih + ROWS;               // f16
    _Float16* wth   = ajh + ROWS;               // f16, 512 halfs

    prep_kernel<<<BB * NN / PR, 256, 0, stream>>>(node, Wn, bn, We1, be1, We2,
                                                  h, tih, ajh, wth);
    edge_kernel<<<BB * NN / IT, 512, 0, stream>>>(tih, ajh, wth, rel, adj, be2,
                                                  h, Wa, ba, node, gamma, beta, out);
}